// Round 6
// baseline (23308.002 us; speedup 1.0000x reference)
//
#include <hip/hip_runtime.h>
#include <math.h>

#define S_LEN 4096
#define HID   2048
#define NBLK  256
#define NTHR  576   // 8 compute waves + 1 dedicated poll wave

typedef unsigned int       u32;
typedef unsigned long long u64;
typedef unsigned u32x4 __attribute__((ext_vector_type(4)));

// R10: dataflow block — dedicated poll wave, ZERO in-loop barriers.
//  Evidence: R4 vs R9 A/B (4x poll-request reduction -> only -2%) falsifies
//  MALL congestion; R8 falsified weight residency. The 6700cy step is serial
//  latency hops in lockstep: publish-visible + detect + [barrier] + stage +
//  full FMA + [barrier] + tail. Fix = overlap everything that can overlap:
//  - wave 8 = poll wave: sweeps all 2048 tagged words (8 dwordx4/lane),
//    stages valid 256-unit chunks into hx_lds[2][2048], posts per-chunk
//    monotonic LDS flags rdyc[parity][chunk]=T. Runs ahead of compute;
//    detection+staging of t+1 overlaps our tail/publish of t.
//  - 8 compute waves: per chunk, LDS flag check -> 16 FMAs; butterfly
//    reduce; gates + per-wave epoch flag gep[parity][wv]=t. No global polls,
//    no __syncthreads. Only the LAST-arriving chunk's FMA sits on the
//    critical path (~100cy) instead of the whole 650cy FMA phase.
//  - wave 0 doubles as tail: parallel spin on 8 gep flags (lane l reads
//    gep[p][l&7], __all), 8-lane tail math, tagged coalesced publish.
//  Monotonic-flag safety (no epoch clobber): rdyc/gep/gates for parity p
//  are overwritten at t+2 only after our publish of t+1, which requires the
//  t-consumers to have finished — same causality proof as the global tags.
//  Global tag scheme unchanged from R9 (validated): value-with-2-LSB-tag,
//  want ((T+1)&3)^2, parity lines exclusive per block, 0xAA poison (tag 2)
//  unreachable: parity-p word polled at T only after all producers published
//  hx_{T-2} (or later) into it; tags of hx_{T-2} and hx_T differ by 2 mod 4.

__device__ __forceinline__ float fast_sigmoid(float x) {
    float e = __builtin_amdgcn_exp2f(-1.44269504f * x);   // 2^(-x*log2e)
    return __builtin_amdgcn_rcpf(1.0f + e);
}

__global__ __launch_bounds__(NTHR, 1)
void qlstm_persistent(const float* __restrict__ inp,     // (S,1,4)
                      const float* __restrict__ conv_w,  // (4)
                      const float* __restrict__ conv_b,  // (1)
                      const float* __restrict__ Wg,      // (2049, 8192) row-major
                      const float* __restrict__ bg,      // (8192)
                      float* __restrict__ out,           // S*H + H + H
                      float* __restrict__ ws)            // scratch (poison 0xAA ok)
{
    const int b   = blockIdx.x;
    const int tid = threadIdx.x;
    const int l   = tid & 63;
    const int wv  = tid >> 6;

    u32* tbl = (u32*)ws;   // [NBLK][16]: exclusive 64B line per block
                           // words 0..7 = parity 0, 8..15 = parity 1

    __shared__ __align__(16) float hx_lds[2][HID];
    __shared__ __align__(16) float conv_lds[S_LEN];
    __shared__ float gates_lds[2][32];
    __shared__ float colw0[32];
    __shared__ float colb[32];
    __shared__ u32 rdyc[2][8];   // per-parity per-chunk ready step (monotonic)
    __shared__ u32 gep[2][8];    // per-parity per-wave gates-epoch

    // ---------------- init phase ----------------
    {
        const float cw0 = conv_w[0], cw1 = conv_w[1], cw2 = conv_w[2], cw3 = conv_w[3];
        const float cb  = conv_b[0];
        for (int g = tid; g < S_LEN; g += NTHR) {
            float4 x = ((const float4*)inp)[g];
            float v = x.x*cw0 + x.y*cw1 + x.z*cw2 + x.w*cw3 + cb;
            conv_lds[g] = fast_sigmoid(v);
        }
    }
    if (tid < 512) ((float4*)hx_lds[0])[tid] = make_float4(0.f, 0.f, 0.f, 0.f);
    if (tid < 16) {
        rdyc[tid >> 3][tid & 7] = 0u;           // parity0: 0>=t(0) ready; parity1 blocks
        gep[tid >> 3][tid & 7]  = 0xFFFFFFFFu;  // != any step
    }

    float wreg[4][32];
    if (wv < 8) {
        // this wave's 4 global column indices
        int jcol[4];
        #pragma unroll
        for (int c = 0; c < 4; ++c) {
            int cgi  = 4*wv + c;
            int gate = cgi >> 3;
            int mi   = cgi & 7;
            jcol[c]  = (gate << 11) + (b * 8 + mi);     // gate*2048 + m
        }
        if (l == 0) {
            #pragma unroll
            for (int c = 0; c < 4; ++c) {
                int cgi = 4*wv + c;
                colw0[cgi] = Wg[jcol[c]];               // row 0 = input weight
                colb[cgi]  = bg[jcol[c]];
            }
        }
        #pragma unroll
        for (int j = 0; j < 8; ++j)
            #pragma unroll
            for (int r = 0; r < 4; ++r) {
                const float* rowp = Wg + (size_t)(1 + 4*l + 256*j + r) * 8192;
                #pragma unroll
                for (int c = 0; c < 4; ++c)
                    wreg[c][4*j + r] = rowp[jcol[c]];
            }
    }

    __syncthreads();    // the ONLY barrier: init complete

    if (wv == 8) {
        // ================= poll wave =================
        __builtin_amdgcn_s_setprio(1);
        // lane l, group g covers units g*256 + 4l .. +3
        //   -> global word (g*32 + (l>>1))*16 + pT*8 + (l&1)*4
        const u32* lane_base = tbl + ((l >> 1) << 4) + ((l & 1) << 2);
        for (int T = 1; T < S_LEN; ++T) {
            const int pT = T & 1;
            const u32 want = ((u32)(T + 1) & 3u) ^ 2u;
            const u32* ap = lane_base + (pT << 3);
            const u32 *a0 = ap,        *a1 = ap + 512,  *a2 = ap + 1024, *a3 = ap + 1536,
                      *a4 = ap + 2048, *a5 = ap + 2560, *a6 = ap + 3072, *a7 = ap + 3584;
            u32x4* dst = (u32x4*)hx_lds[pT];
            u32 bits = 0, prev = 0, ldone = 0;
            do {
                u32x4 q0, q1, q2, q3, q4, q5, q6, q7;
                asm volatile(
                    "global_load_dwordx4 %0, %8,  off sc0 sc1\n\t"
                    "global_load_dwordx4 %1, %9,  off sc0 sc1\n\t"
                    "global_load_dwordx4 %2, %10, off sc0 sc1\n\t"
                    "global_load_dwordx4 %3, %11, off sc0 sc1\n\t"
                    "global_load_dwordx4 %4, %12, off sc0 sc1\n\t"
                    "global_load_dwordx4 %5, %13, off sc0 sc1\n\t"
                    "global_load_dwordx4 %6, %14, off sc0 sc1\n\t"
                    "global_load_dwordx4 %7, %15, off sc0 sc1\n\t"
                    "s_waitcnt vmcnt(0)"
                    : "=&v"(q0), "=&v"(q1), "=&v"(q2), "=&v"(q3),
                      "=&v"(q4), "=&v"(q5), "=&v"(q6), "=&v"(q7)
                    : "v"(a0), "v"(a1), "v"(a2), "v"(a3),
                      "v"(a4), "v"(a5), "v"(a6), "v"(a7)
                    : "memory");
                #define GRP(g, qq)                                               \
                    if (!(bits & (1u << g))) {                                   \
                        bool ok = ((qq[0] & 3u) == want) && ((qq[1] & 3u) == want) \
                               && ((qq[2] & 3u) == want) && ((qq[3] & 3u) == want); \
                        if (ok && !(ldone & (1u << g))) {                        \
                            u32x4 st;                                            \
                            st[0] = qq[0] & ~3u; st[1] = qq[1] & ~3u;            \
                            st[2] = qq[2] & ~3u; st[3] = qq[3] & ~3u;            \
                            dst[(g << 6) + l] = st;                              \
                            ldone |= 1u << g;                                    \
                        }                                                        \
                        if (__ballot(ok) == ~0ull) bits |= 1u << g;              \
                    }
                GRP(0, q0) GRP(1, q1) GRP(2, q2) GRP(3, q3)
                GRP(4, q4) GRP(5, q5) GRP(6, q6) GRP(7, q7)
                #undef GRP
                u32 newbits = bits & ~prev;
                if (l == 0 && newbits) {
                    #pragma unroll
                    for (int g = 0; g < 8; ++g)
                        if (newbits & (1u << g))
                            __hip_atomic_store(&rdyc[pT][g], (u32)T,
                                               __ATOMIC_RELEASE,
                                               __HIP_MEMORY_SCOPE_WORKGROUP);
                }
                prev = bits;
            } while (bits != 0xFFu);
        }
    } else {
        // ================= compute waves =================
        float cx = 0.0f;                     // live in wave-0 lanes<8
        const int m_out = b * 8 + l;
        for (int t = 0; t < S_LEN; ++t) {
            const int p = t & 1;
            const u32 ut = (u32)t;
            const float4* hl = (const float4*)hx_lds[p];

            // pipelined fast-path flag check
            u32 mready = 0;
            #pragma unroll
            for (int j = 0; j < 8; ++j)
                mready |= (__hip_atomic_load(&rdyc[p][j], __ATOMIC_RELAXED,
                                             __HIP_MEMORY_SCOPE_WORKGROUP) >= ut)
                          ? (1u << j) : 0u;
            __threadfence_block();

            float acc0 = 0.f, acc1 = 0.f, acc2 = 0.f, acc3 = 0.f;
            #pragma unroll
            for (int j = 0; j < 8; ++j) {
                if (!(mready & (1u << j))) {
                    u32 r;
                    do { r = __hip_atomic_load(&rdyc[p][j], __ATOMIC_RELAXED,
                                               __HIP_MEMORY_SCOPE_WORKGROUP); }
                    while (r < ut);
                    __threadfence_block();
                }
                float4 h = hl[l + 64*j];        // ds_read_b128, conflict-free
                acc0 = fmaf(h.x, wreg[0][4*j+0], acc0);
                acc1 = fmaf(h.x, wreg[1][4*j+0], acc1);
                acc2 = fmaf(h.x, wreg[2][4*j+0], acc2);
                acc3 = fmaf(h.x, wreg[3][4*j+0], acc3);
                acc0 = fmaf(h.y, wreg[0][4*j+1], acc0);
                acc1 = fmaf(h.y, wreg[1][4*j+1], acc1);
                acc2 = fmaf(h.y, wreg[2][4*j+1], acc2);
                acc3 = fmaf(h.y, wreg[3][4*j+1], acc3);
                acc0 = fmaf(h.z, wreg[0][4*j+2], acc0);
                acc1 = fmaf(h.z, wreg[1][4*j+2], acc1);
                acc2 = fmaf(h.z, wreg[2][4*j+2], acc2);
                acc3 = fmaf(h.z, wreg[3][4*j+2], acc3);
                acc0 = fmaf(h.w, wreg[0][4*j+3], acc0);
                acc1 = fmaf(h.w, wreg[1][4*j+3], acc1);
                acc2 = fmaf(h.w, wreg[2][4*j+3], acc2);
                acc3 = fmaf(h.w, wreg[3][4*j+3], acc3);
            }
            #pragma unroll
            for (int off = 32; off; off >>= 1) {
                acc0 += __shfl_down(acc0, off, 64);
                acc1 += __shfl_down(acc1, off, 64);
                acc2 += __shfl_down(acc2, off, 64);
                acc3 += __shfl_down(acc3, off, 64);
            }
            if (l == 0) {
                gates_lds[p][4*wv + 0] = acc0;
                gates_lds[p][4*wv + 1] = acc1;
                gates_lds[p][4*wv + 2] = acc2;
                gates_lds[p][4*wv + 3] = acc3;
                __hip_atomic_store(&gep[p][wv], ut, __ATOMIC_RELEASE,
                                   __HIP_MEMORY_SCOPE_WORKGROUP);
            }

            if (wv == 0) {
                // parallel spin: lane l watches gep[p][l&7]
                u32 g;
                do { g = __hip_atomic_load(&gep[p][l & 7], __ATOMIC_ACQUIRE,
                                           __HIP_MEMORY_SCOPE_WORKGROUP); }
                while (!__all(g == ut));
                __builtin_amdgcn_s_setprio(1);
                if (l < 8) {
                    float ct = conv_lds[t];
                    float fg = gates_lds[p][l]      + ct*colw0[l]      + colb[l];
                    float ig = gates_lds[p][8 + l]  + ct*colw0[8 + l]  + colb[8 + l];
                    float gg = gates_lds[p][16 + l] + ct*colw0[16 + l] + colb[16 + l];
                    float og = gates_lds[p][24 + l] + ct*colw0[24 + l] + colb[24 + l];
                    float f  = fast_sigmoid(fg);
                    float ii = fast_sigmoid(ig);
                    float gv = 2.0f * fast_sigmoid(2.0f * gg) - 1.0f;   // tanh
                    float o  = fast_sigmoid(og);
                    cx = f * cx + ii * gv;
                    float hx = o * (2.0f * fast_sigmoid(2.0f * cx) - 1.0f);
                    if (t < S_LEN - 1) {
                        u32 word = (__float_as_uint(hx) & ~3u)
                                 | (((u32)(t + 2) & 3u) ^ 2u);
                        __hip_atomic_store(tbl + b*16 + (((t + 1) & 1) << 3) + l,
                                           word, __ATOMIC_RELAXED,
                                           __HIP_MEMORY_SCOPE_AGENT);
                    }
                    out[(size_t)t * HID + m_out] = hx;
                    if (t == S_LEN - 1) {
                        out[(size_t)S_LEN * HID + m_out]       = hx;   // final hx
                        out[(size_t)S_LEN * HID + HID + m_out] = cx;   // final cx
                    }
                }
                __builtin_amdgcn_s_setprio(0);
            }
        }
    }
}

extern "C" void kernel_launch(void* const* d_in, const int* in_sizes, int n_in,
                              void* d_out, int out_size, void* d_ws, size_t ws_size,
                              hipStream_t stream) {
    const float* inp    = (const float*)d_in[0];
    const float* conv_w = (const float*)d_in[1];
    const float* conv_b = (const float*)d_in[2];
    const float* Wg     = (const float*)d_in[3];
    const float* bg     = (const float*)d_in[4];
    float* out = (float*)d_out;
    float* ws  = (float*)d_ws;

    void* args[] = {(void*)&inp, (void*)&conv_w, (void*)&conv_b,
                    (void*)&Wg, (void*)&bg, (void*)&out, (void*)&ws};
    hipLaunchCooperativeKernel((void*)qlstm_persistent,
                               dim3(NBLK), dim3(NTHR), args, 0, stream);
}

// Round 7
// 16916.087 us; speedup vs baseline: 1.3779x; 1.3779x over previous
//
#include <hip/hip_runtime.h>
#include <math.h>

#define S_LEN 4096
#define HID   2048
#define NBLK  256
#define NTHR  512   // 8 waves/block, 1 block/CU

typedef unsigned int       u32;
typedef unsigned long long u64;
typedef unsigned u32x4 __attribute__((ext_vector_type(4)));

// R11 = R9 (best, 11.45ms) with ONE change: pipelined uniformly-paced polling.
//  R9's poll was serial (load; vmcnt(0); check): samples spaced a full MALL
//  RTT (R) apart -> per-thread detection = R/2 + U[0,R), and barrier A waits
//  for the MAX over 512 threads' phases ~= R/2 + R. The quantization term is
//  ~a full RTT per step (~0.4-0.8us of the 2.8us step).
//  Fix: 8-slot in-flight ring to the SAME 16B address, issues staggered by
//  s_sleep(2) (~130cy) -> uniform sampling at ~max(R/8,160cy) spacing ->
//  max-over-threads detection term drops from ~R to ~160cy.
//  Ring invariant: checked slot is always the oldest in flight; on hit, all
//  in-flight loads sampled at-or-after the hit sample and the polled word
//  cannot advance past tag==want while anyone still polls step t (the writer
//  block can only publish t+2 after it consumed t+1, which needs OUR t+1
//  publish) -> after vmcnt(0) ALL slots hold the want value; use slot 0.
//  Hazard discipline (guide rule #18): every s_waitcnt asm carries "+v" on
//  the slot it guards so the compiler cannot hoist the tag-check above it.
//  R10's poll-wave specialization REVERTED (23.3ms: ballot-gated flags +
//  volley-quantized sweeps + LDS flag-spin contention added a serial hop).
//  Kept from R9 (validated): value-with-2-LSB-tag entries, want ((t+1)&3)^2,
//  exclusive 64B line per block (words 0..7 parity0, 8..15 parity1), 0xAA
//  poison unreachable, coalesced 32B publish from 8-lane tail, fast exp2
//  sigmoid/tanh, setprio(1) around tail, conv precompute, hx_0 prestaged.

__device__ __forceinline__ float fast_sigmoid(float x) {
    float e = __builtin_amdgcn_exp2f(-1.44269504f * x);   // 2^(-x*log2e)
    return __builtin_amdgcn_rcpf(1.0f + e);
}

__global__ __launch_bounds__(NTHR, 2)
void qlstm_persistent(const float* __restrict__ inp,     // (S,1,4)
                      const float* __restrict__ conv_w,  // (4)
                      const float* __restrict__ conv_b,  // (1)
                      const float* __restrict__ Wg,      // (2049, 8192) row-major
                      const float* __restrict__ bg,      // (8192)
                      float* __restrict__ out,           // S*H + H + H
                      float* __restrict__ ws)            // scratch (poison 0xAA ok)
{
    const int b   = blockIdx.x;
    const int tid = threadIdx.x;
    const int l   = tid & 63;
    const int wv  = tid >> 6;

    u32* tbl = (u32*)ws;   // [NBLK][16]: exclusive 64B line per block

    __shared__ __align__(16) float hx_lds[HID];
    __shared__ __align__(16) float conv_lds[S_LEN];
    __shared__ float gates_lds[32];
    __shared__ float colw0[32];
    __shared__ float colb[32];

    // ---------------- init phase ----------------
    {
        const float cw0 = conv_w[0], cw1 = conv_w[1], cw2 = conv_w[2], cw3 = conv_w[3];
        const float cb  = conv_b[0];
        for (int g = tid; g < S_LEN; g += NTHR) {
            float4 x = ((const float4*)inp)[g];
            float v = x.x*cw0 + x.y*cw1 + x.z*cw2 + x.w*cw3 + cb;
            conv_lds[g] = fast_sigmoid(v);
        }
    }
    // hx_0 = 0 lives purely in LDS: step 0 needs no global exchange at all.
    ((float4*)hx_lds)[tid] = make_float4(0.f, 0.f, 0.f, 0.f);

    // this wave's 4 global column indices
    int jcol[4];
    #pragma unroll
    for (int c = 0; c < 4; ++c) {
        int cgi  = 4*wv + c;
        int gate = cgi >> 3;
        int mi   = cgi & 7;
        jcol[c]  = (gate << 11) + (b * 8 + mi);     // gate*2048 + m
    }
    if (l == 0) {
        #pragma unroll
        for (int c = 0; c < 4; ++c) {
            int cgi = 4*wv + c;
            colw0[cgi] = Wg[jcol[c]];               // row 0 = input (c_t) weight
            colb[cgi]  = bg[jcol[c]];
        }
    }

    // W registers: wreg[c][4j+r] = W[1 + 4l + 256j + r][jcol[c]]
    float wreg[4][32];
    #pragma unroll
    for (int j = 0; j < 8; ++j)
        #pragma unroll
        for (int r = 0; r < 4; ++r) {
            const float* rowp = Wg + (size_t)(1 + 4*l + 256*j + r) * 8192;
            #pragma unroll
            for (int c = 0; c < 4; ++c)
                wreg[c][4*j + r] = rowp[jcol[c]];
        }

    float cx = 0.0f;                    // live only in lanes tid<8
    const int m_out = b * 8 + tid;      // hidden index for tid<8

    // thread tid polls units 4*tid..4*tid+3: block tid>>1, units (tid&1)*4+k
    const u32* poll_base = tbl + (tid >> 1) * 16 + (tid & 1) * 4;
    u32* pub_base = tbl + b * 16 + tid;      // + parity*8 at publish (tid<8)

    // ---------------- recurrence ----------------
    for (int t = 0; t < S_LEN; ++t) {
        if (t) {
            const u32 want = ((u32)(t + 1) & 3u) ^ 2u;
            const u32* pp = poll_base + ((t & 1) << 3);   // parity half-line

            u32x4 q0, q1, q2, q3, q4, q5, q6, q7;
            // staggered prime: uniform sampling from the first lap
            #define PRIME(qq)                                                  \
                asm volatile("global_load_dwordx4 %0, %1, off sc0 sc1"         \
                             : "=v"(qq) : "v"(pp) : "memory");                 \
                __builtin_amdgcn_s_sleep(2);
            PRIME(q0) PRIME(q1) PRIME(q2) PRIME(q3)
            PRIME(q4) PRIME(q5) PRIME(q6) PRIME(q7)
            #undef PRIME

            // ring: checked slot is always the oldest of the 8 in flight
            #define POLL_SLOT(qq)                                              \
                asm volatile("s_waitcnt vmcnt(7)" : "+v"(qq) :: "memory");     \
                if (((qq[0] & 3u) == want) & ((qq[1] & 3u) == want) &          \
                    ((qq[2] & 3u) == want) & ((qq[3] & 3u) == want)) break;    \
                asm volatile("global_load_dwordx4 %0, %1, off sc0 sc1"         \
                             : "=v"(qq) : "v"(pp) : "memory");                 \
                __builtin_amdgcn_s_sleep(2);
            for (;;) {
                POLL_SLOT(q0) POLL_SLOT(q1) POLL_SLOT(q2) POLL_SLOT(q3)
                POLL_SLOT(q4) POLL_SLOT(q5) POLL_SLOT(q6) POLL_SLOT(q7)
            }
            #undef POLL_SLOT
            // drain: all in-flight loads sampled at-or-after the hit ->
            // every slot now holds the want-tagged value; q0 is safe to use.
            asm volatile("s_waitcnt vmcnt(0)" : "+v"(q0) :: "memory");
            __builtin_amdgcn_sched_barrier(0);

            u32x4 st;
            st[0] = q0[0] & ~3u; st[1] = q0[1] & ~3u;
            st[2] = q0[2] & ~3u; st[3] = q0[3] & ~3u;
            ((u32x4*)hx_lds)[tid] = st;     // units 4*tid..+3, ds_write_b128
        }
        __syncthreads();                    // A: hx_t staged

        // ---- 2048-MAC dot for this wave's 4 gate columns ----
        const float4* hl = (const float4*)hx_lds;
        float acc0 = 0.f, acc1 = 0.f, acc2 = 0.f, acc3 = 0.f;
        #pragma unroll
        for (int j = 0; j < 8; ++j) {
            float4 h = hl[l + 64*j];        // ds_read_b128, conflict-free
            acc0 = fmaf(h.x, wreg[0][4*j+0], acc0);
            acc1 = fmaf(h.x, wreg[1][4*j+0], acc1);
            acc2 = fmaf(h.x, wreg[2][4*j+0], acc2);
            acc3 = fmaf(h.x, wreg[3][4*j+0], acc3);
            acc0 = fmaf(h.y, wreg[0][4*j+1], acc0);
            acc1 = fmaf(h.y, wreg[1][4*j+1], acc1);
            acc2 = fmaf(h.y, wreg[2][4*j+1], acc2);
            acc3 = fmaf(h.y, wreg[3][4*j+1], acc3);
            acc0 = fmaf(h.z, wreg[0][4*j+2], acc0);
            acc1 = fmaf(h.z, wreg[1][4*j+2], acc1);
            acc2 = fmaf(h.z, wreg[2][4*j+2], acc2);
            acc3 = fmaf(h.z, wreg[3][4*j+2], acc3);
            acc0 = fmaf(h.w, wreg[0][4*j+3], acc0);
            acc1 = fmaf(h.w, wreg[1][4*j+3], acc1);
            acc2 = fmaf(h.w, wreg[2][4*j+3], acc2);
            acc3 = fmaf(h.w, wreg[3][4*j+3], acc3);
        }
        #pragma unroll
        for (int off = 32; off; off >>= 1) {
            acc0 += __shfl_down(acc0, off, 64);
            acc1 += __shfl_down(acc1, off, 64);
            acc2 += __shfl_down(acc2, off, 64);
            acc3 += __shfl_down(acc3, off, 64);
        }
        if (l == 0) {
            gates_lds[4*wv + 0] = acc0;
            gates_lds[4*wv + 1] = acc1;
            gates_lds[4*wv + 2] = acc2;
            gates_lds[4*wv + 3] = acc3;
        }
        __syncthreads();                    // B: gates complete

        if (wv == 0) __builtin_amdgcn_s_setprio(1);   // publisher outranks spinners
        if (tid < 8) {
            float ct = conv_lds[t];
            float fg = gates_lds[tid]      + ct*colw0[tid]      + colb[tid];
            float ig = gates_lds[8 + tid]  + ct*colw0[8 + tid]  + colb[8 + tid];
            float gg = gates_lds[16 + tid] + ct*colw0[16 + tid] + colb[16 + tid];
            float og = gates_lds[24 + tid] + ct*colw0[24 + tid] + colb[24 + tid];
            float f  = fast_sigmoid(fg);
            float ii = fast_sigmoid(ig);
            float gv = 2.0f * fast_sigmoid(2.0f * gg) - 1.0f;   // tanh
            float o  = fast_sigmoid(og);
            cx = f * cx + ii * gv;
            float hx = o * (2.0f * fast_sigmoid(2.0f * cx) - 1.0f);
            // publish hx_{t+1} into parity (t+1)&1 of the block's OWN line:
            // 8 lanes -> one 32B store, line never shared with another block.
            u32 word = (__float_as_uint(hx) & ~3u) | (((u32)(t + 2) & 3u) ^ 2u);
            __hip_atomic_store(pub_base + (((t + 1) & 1) << 3), word,
                               __ATOMIC_RELAXED, __HIP_MEMORY_SCOPE_AGENT);
            out[(size_t)t * HID + m_out] = hx;
            if (t == S_LEN - 1) {
                out[(size_t)S_LEN * HID + m_out]       = hx;   // final hx
                out[(size_t)S_LEN * HID + HID + m_out] = cx;   // final cx
            }
        }
        if (wv == 0) __builtin_amdgcn_s_setprio(0);
    }
}

extern "C" void kernel_launch(void* const* d_in, const int* in_sizes, int n_in,
                              void* d_out, int out_size, void* d_ws, size_t ws_size,
                              hipStream_t stream) {
    const float* inp    = (const float*)d_in[0];
    const float* conv_w = (const float*)d_in[1];
    const float* conv_b = (const float*)d_in[2];
    const float* Wg     = (const float*)d_in[3];
    const float* bg     = (const float*)d_in[4];
    float* out = (float*)d_out;
    float* ws  = (float*)d_ws;

    // no memset needed: poison tag (0xAA..&3 == 2) only aliases parity-1's
    // t=3 want, and every parity-1 word is overwritten at t=0 and t=2 first;
    // same-address coherence is monotonic, so poison is unreachable.
    void* args[] = {(void*)&inp, (void*)&conv_w, (void*)&conv_b,
                    (void*)&Wg, (void*)&bg, (void*)&out, (void*)&ws};
    hipLaunchCooperativeKernel((void*)qlstm_persistent,
                               dim3(NBLK), dim3(NTHR), args, 0, stream);
}

// Round 8
// 11287.241 us; speedup vs baseline: 2.0650x; 1.4987x over previous
//
#include <hip/hip_runtime.h>
#include <math.h>

#define S_LEN 4096
#define HID   2048
#define NBLK  256
#define NTHR  512   // 8 waves/block, 1 block/CU

typedef unsigned int       u32;
typedef unsigned long long u64;
typedef unsigned u32x4 __attribute__((ext_vector_type(4)));

// R12 = R9 (best, 11.45ms) + counter gate: shrink the poller population.
//  Model (consolidated from R4~R9, R10, R11 A/Bs): the coherence point is
//  service-rate-saturated by ~131K closed-loop pollers; each thread is
//  served every N/C cycles (C ~ 20-40 req/cy) -> detection phase ~3-5k cy
//  regardless of per-thread pacing. R4 vs R9 (4x fewer requests/thread,
//  -2%) and R11 (pacing, worse) both support the population model.
//  Fix: publishers also atomicAdd one of 8 counters (64B-spaced lines,
//  32 adds/counter/step). Per block only wave 7 lanes 0-7 poll counters
//  (2K pollers chip-wide); on all-8 >= 32*(t-1), lane 0 raises an LDS
//  flag; the other 511 threads spin on LDS (broadcast, no MALL traffic),
//  then everyone does ONE tag-verified dwordx4 volley (R9's exact loop,
//  now expected first-lap hit). Tags stay the correctness net; counters
//  are only a hint -> no new ordering requirements anywhere.
//  Init safety: blocks 0-7 store cnt[b]=0 during init (drained by the
//  t=0 __syncthreads before any tag publish); earliest add is end of
//  iter 1, causally after every consumer of iter-0 tags -> no race.
//  t=1 uses the ungated R9 loop once (counters have no history yet).
//  Kept from R9 (validated): value-with-2-LSB-tag entries, want
//  ((t+1)&3)^2, exclusive 64B line per block (words 0..7 parity0, 8..15
//  parity1), 0xAA poison unreachable, coalesced 32B publish from 8-lane
//  tail, fast exp2 sigmoid/tanh, setprio(1) around tail, conv precompute,
//  hx_0 prestaged (no t=0 exchange).

__device__ __forceinline__ float fast_sigmoid(float x) {
    float e = __builtin_amdgcn_exp2f(-1.44269504f * x);   // 2^(-x*log2e)
    return __builtin_amdgcn_rcpf(1.0f + e);
}

__global__ __launch_bounds__(NTHR, 2)
void qlstm_persistent(const float* __restrict__ inp,     // (S,1,4)
                      const float* __restrict__ conv_w,  // (4)
                      const float* __restrict__ conv_b,  // (1)
                      const float* __restrict__ Wg,      // (2049, 8192) row-major
                      const float* __restrict__ bg,      // (8192)
                      float* __restrict__ out,           // S*H + H + H
                      float* __restrict__ ws)            // scratch (poison 0xAA ok)
{
    const int b   = blockIdx.x;
    const int tid = threadIdx.x;
    const int l   = tid & 63;
    const int wv  = tid >> 6;

    u32* tbl = (u32*)ws;            // [NBLK][16]: exclusive 64B line per block
    u32* cnt = (u32*)ws + 4096;     // 8 counters, 64B apart (own lines)

    __shared__ __align__(16) float hx_lds[HID];
    __shared__ __align__(16) float conv_lds[S_LEN];
    __shared__ float gates_lds[32];
    __shared__ float colw0[32];
    __shared__ float colb[32];
    __shared__ u32 goflag;

    // ---------------- init phase ----------------
    {
        const float cw0 = conv_w[0], cw1 = conv_w[1], cw2 = conv_w[2], cw3 = conv_w[3];
        const float cb  = conv_b[0];
        for (int g = tid; g < S_LEN; g += NTHR) {
            float4 x = ((const float4*)inp)[g];
            float v = x.x*cw0 + x.y*cw1 + x.z*cw2 + x.w*cw3 + cb;
            conv_lds[g] = fast_sigmoid(v);
        }
    }
    // hx_0 = 0 lives purely in LDS: step 0 needs no global exchange at all.
    ((float4*)hx_lds)[tid] = make_float4(0.f, 0.f, 0.f, 0.f);
    if (tid == 0) goflag = 1u;                   // < 2: first gated iter spins
    if (b < 8 && tid == 0)                        // counter init (see header)
        __hip_atomic_store(&cnt[b * 16], 0u,
                           __ATOMIC_RELAXED, __HIP_MEMORY_SCOPE_AGENT);

    // this wave's 4 global column indices
    int jcol[4];
    #pragma unroll
    for (int c = 0; c < 4; ++c) {
        int cgi  = 4*wv + c;
        int gate = cgi >> 3;
        int mi   = cgi & 7;
        jcol[c]  = (gate << 11) + (b * 8 + mi);     // gate*2048 + m
    }
    if (l == 0) {
        #pragma unroll
        for (int c = 0; c < 4; ++c) {
            int cgi = 4*wv + c;
            colw0[cgi] = Wg[jcol[c]];               // row 0 = input (c_t) weight
            colb[cgi]  = bg[jcol[c]];
        }
    }

    // W registers: wreg[c][4j+r] = W[1 + 4l + 256j + r][jcol[c]]
    float wreg[4][32];
    #pragma unroll
    for (int j = 0; j < 8; ++j)
        #pragma unroll
        for (int r = 0; r < 4; ++r) {
            const float* rowp = Wg + (size_t)(1 + 4*l + 256*j + r) * 8192;
            #pragma unroll
            for (int c = 0; c < 4; ++c)
                wreg[c][4*j + r] = rowp[jcol[c]];
        }

    float cx = 0.0f;                    // live only in lanes tid<8
    const int m_out = b * 8 + tid;      // hidden index for tid<8

    // thread tid polls units 4*tid..4*tid+3: block tid>>1, units (tid&1)*4+k
    const u32* poll_base = tbl + (tid >> 1) * 16 + (tid & 1) * 4;
    u32* pub_base = tbl + b * 16 + tid;      // + parity*8 at publish (tid<8)

    // ---------------- recurrence ----------------
    for (int t = 0; t < S_LEN; ++t) {
        if (t) {
            // ---- gate (t>=2): wave 7 polls 8 counters; rest spin on LDS ----
            if (t >= 2) {
                const u32 tgt = 32u * (u32)(t - 1);
                if (wv == 7) {
                    u32 c;
                    do {
                        c = tgt;
                        if (l < 8)
                            c = __hip_atomic_load(&cnt[l * 16], __ATOMIC_RELAXED,
                                                  __HIP_MEMORY_SCOPE_AGENT);
                    } while (!__all(c >= tgt));
                    if (l == 0)
                        __hip_atomic_store(&goflag, (u32)t, __ATOMIC_RELAXED,
                                           __HIP_MEMORY_SCOPE_WORKGROUP);
                } else {
                    while (__hip_atomic_load(&goflag, __ATOMIC_RELAXED,
                                             __HIP_MEMORY_SCOPE_WORKGROUP) < (u32)t) {}
                }
            }

            // ---- one-shot tag-verified volley (R9's loop; retries rare) ----
            const u32 want = ((u32)(t + 1) & 3u) ^ 2u;
            const u32* pp = poll_base + ((t & 1) << 3);   // parity half-line
            u32x4 q;
            u32 miss;
            do {
                asm volatile("global_load_dwordx4 %0, %1, off sc0 sc1\n\t"
                             "s_waitcnt vmcnt(0)"
                             : "=v"(q) : "v"(pp) : "memory");
                miss = ((q[0] ^ want) & 3u) | ((q[1] ^ want) & 3u)
                     | ((q[2] ^ want) & 3u) | ((q[3] ^ want) & 3u);
            } while (miss);
            u32x4 st;
            st[0] = q[0] & ~3u; st[1] = q[1] & ~3u;
            st[2] = q[2] & ~3u; st[3] = q[3] & ~3u;
            ((u32x4*)hx_lds)[tid] = st;     // units 4*tid..+3, ds_write_b128
        }
        __syncthreads();                    // A: hx_t staged

        // ---- 2048-MAC dot for this wave's 4 gate columns ----
        const float4* hl = (const float4*)hx_lds;
        float acc0 = 0.f, acc1 = 0.f, acc2 = 0.f, acc3 = 0.f;
        #pragma unroll
        for (int j = 0; j < 8; ++j) {
            float4 h = hl[l + 64*j];        // ds_read_b128, conflict-free
            acc0 = fmaf(h.x, wreg[0][4*j+0], acc0);
            acc1 = fmaf(h.x, wreg[1][4*j+0], acc1);
            acc2 = fmaf(h.x, wreg[2][4*j+0], acc2);
            acc3 = fmaf(h.x, wreg[3][4*j+0], acc3);
            acc0 = fmaf(h.y, wreg[0][4*j+1], acc0);
            acc1 = fmaf(h.y, wreg[1][4*j+1], acc1);
            acc2 = fmaf(h.y, wreg[2][4*j+1], acc2);
            acc3 = fmaf(h.y, wreg[3][4*j+1], acc3);
            acc0 = fmaf(h.z, wreg[0][4*j+2], acc0);
            acc1 = fmaf(h.z, wreg[1][4*j+2], acc1);
            acc2 = fmaf(h.z, wreg[2][4*j+2], acc2);
            acc3 = fmaf(h.z, wreg[3][4*j+2], acc3);
            acc0 = fmaf(h.w, wreg[0][4*j+3], acc0);
            acc1 = fmaf(h.w, wreg[1][4*j+3], acc1);
            acc2 = fmaf(h.w, wreg[2][4*j+3], acc2);
            acc3 = fmaf(h.w, wreg[3][4*j+3], acc3);
        }
        #pragma unroll
        for (int off = 32; off; off >>= 1) {
            acc0 += __shfl_down(acc0, off, 64);
            acc1 += __shfl_down(acc1, off, 64);
            acc2 += __shfl_down(acc2, off, 64);
            acc3 += __shfl_down(acc3, off, 64);
        }
        if (l == 0) {
            gates_lds[4*wv + 0] = acc0;
            gates_lds[4*wv + 1] = acc1;
            gates_lds[4*wv + 2] = acc2;
            gates_lds[4*wv + 3] = acc3;
        }
        __syncthreads();                    // B: gates complete

        if (wv == 0) __builtin_amdgcn_s_setprio(1);   // publisher outranks spinners
        if (tid < 8) {
            float ct = conv_lds[t];
            float fg = gates_lds[tid]      + ct*colw0[tid]      + colb[tid];
            float ig = gates_lds[8 + tid]  + ct*colw0[8 + tid]  + colb[8 + tid];
            float gg = gates_lds[16 + tid] + ct*colw0[16 + tid] + colb[16 + tid];
            float og = gates_lds[24 + tid] + ct*colw0[24 + tid] + colb[24 + tid];
            float f  = fast_sigmoid(fg);
            float ii = fast_sigmoid(ig);
            float gv = 2.0f * fast_sigmoid(2.0f * gg) - 1.0f;   // tanh
            float o  = fast_sigmoid(og);
            cx = f * cx + ii * gv;
            float hx = o * (2.0f * fast_sigmoid(2.0f * cx) - 1.0f);
            // publish hx_{t+1} into parity (t+1)&1 of the block's OWN line:
            // 8 lanes -> one 32B store, line never shared with another block.
            u32 word = (__float_as_uint(hx) & ~3u) | (((u32)(t + 2) & 3u) ^ 2u);
            __hip_atomic_store(pub_base + (((t + 1) & 1) << 3), word,
                               __ATOMIC_RELAXED, __HIP_MEMORY_SCOPE_AGENT);
            // counter bump: issued after the tag store (program order);
            // reordering at the MALL only risks a rare volley retry.
            if (tid == 0)
                __hip_atomic_fetch_add(&cnt[(b >> 5) * 16], 1u,
                                       __ATOMIC_RELAXED, __HIP_MEMORY_SCOPE_AGENT);
            out[(size_t)t * HID + m_out] = hx;
            if (t == S_LEN - 1) {
                out[(size_t)S_LEN * HID + m_out]       = hx;   // final hx
                out[(size_t)S_LEN * HID + HID + m_out] = cx;   // final cx
            }
        }
        if (wv == 0) __builtin_amdgcn_s_setprio(0);
    }
}

extern "C" void kernel_launch(void* const* d_in, const int* in_sizes, int n_in,
                              void* d_out, int out_size, void* d_ws, size_t ws_size,
                              hipStream_t stream) {
    const float* inp    = (const float*)d_in[0];
    const float* conv_w = (const float*)d_in[1];
    const float* conv_b = (const float*)d_in[2];
    const float* Wg     = (const float*)d_in[3];
    const float* bg     = (const float*)d_in[4];
    float* out = (float*)d_out;
    float* ws  = (float*)d_ws;

    // no memset needed: tag poison unreachable (R9 proof); counters are
    // kernel-initialized by blocks 0-7 before any add can occur.
    void* args[] = {(void*)&inp, (void*)&conv_w, (void*)&conv_b,
                    (void*)&Wg, (void*)&bg, (void*)&out, (void*)&ws};
    hipLaunchCooperativeKernel((void*)qlstm_persistent,
                               dim3(NBLK), dim3(NTHR), args, 0, stream);
}